// Round 1
// baseline (5460.546 us; speedup 1.0000x reference)
//
#include <hip/hip_runtime.h>
#include <math.h>

#define BB 16
#define NN 2048

__device__ __forceinline__ float leaky(float z) { return z > 0.f ? z : 0.2f * z; }
__device__ __forceinline__ float bnscale(float g) { return g / sqrtf(1.f + 1e-5f); }

// ---------------------------------------------------------------------------
// Wave-level top-K extraction. Each lane holds 32 candidate dists (j = lane*32+m).
// Extract K maxima (ties -> smaller j), write indices to out[0..K).
// ---------------------------------------------------------------------------
template<int K>
__device__ __forceinline__ void wave_topk(float lv[32], int lane, int* out) {
    for (int k = 0; k < K; ++k) {
        float bv = -INFINITY; int bj = 0;
        #pragma unroll
        for (int m = 0; m < 32; ++m) {
            float v = lv[m];
            bool t = v > bv;              // strict > keeps smallest j within lane
            bv = t ? v : bv;
            bj = t ? (lane * 32 + m) : bj;
        }
        #pragma unroll
        for (int off = 1; off < 64; off <<= 1) {
            float ov = __shfl_xor(bv, off);
            int   oj = __shfl_xor(bj, off);
            if (ov > bv || (ov == bv && oj < bj)) { bv = ov; bj = oj; }
        }
        if (lane == 0) out[k] = bj;
        #pragma unroll
        for (int m = 0; m < 32; ++m)
            if (lane * 32 + m == bj) lv[m] = -INFINITY;
    }
}

// ---------------------------------------------------------------------------
// Kernel 1: top-30 neighbors on raw xyz. x: [B,3,N]. 4 rows per block.
// ---------------------------------------------------------------------------
__global__ __launch_bounds__(256) void topk_xyz(const float* __restrict__ x,
                                                int* __restrict__ idx30) {
    const int tile = blockIdx.x;                 // b*512 + it
    const int b = tile >> 9;
    const int i0 = (tile & 511) * 4;
    __shared__ float dist[4][NN];
    const float* xb = x + (size_t)b * 3 * NN;
    float xi[4][3], ni[4];
    #pragma unroll
    for (int t = 0; t < 4; ++t) {
        xi[t][0] = xb[i0 + t];
        xi[t][1] = xb[NN + i0 + t];
        xi[t][2] = xb[2 * NN + i0 + t];
        ni[t] = xi[t][0] * xi[t][0] + xi[t][1] * xi[t][1] + xi[t][2] * xi[t][2];
    }
    for (int j = threadIdx.x; j < NN; j += 256) {
        float a0 = xb[j], a1 = xb[NN + j], a2 = xb[2 * NN + j];
        float nj = a0 * a0 + a1 * a1 + a2 * a2;
        #pragma unroll
        for (int t = 0; t < 4; ++t) {
            float dot = xi[t][0] * a0 + xi[t][1] * a1 + xi[t][2] * a2;
            dist[t][j] = 2.f * dot - ni[t] - nj;
        }
    }
    __syncthreads();
    const int w = threadIdx.x >> 6;
    const int lane = threadIdx.x & 63;
    float lv[32];
    #pragma unroll
    for (int m = 0; m < 32; ++m) lv[m] = dist[w][lane * 32 + m];
    wave_topk<30>(lv, lane, idx30 + ((size_t)b * NN + i0 + w) * 30);
}

// ---------------------------------------------------------------------------
// Kernel 2: hierarchical scale convs (k=5/20/30) + fused wf conv -> x1 [B,N,64]
// ---------------------------------------------------------------------------
__global__ __launch_bounds__(64) void hier_conv(
        const float* __restrict__ x, const int* __restrict__ idx30,
        const float* __restrict__ w1l, const float* __restrict__ g1l, const float* __restrict__ b1l,
        const float* __restrict__ w1b, const float* __restrict__ g1b, const float* __restrict__ b1b,
        const float* __restrict__ w1c, const float* __restrict__ g1c, const float* __restrict__ b1c,
        const float* __restrict__ wf,  const float* __restrict__ gf,  const float* __restrict__ bf_,
        float* __restrict__ x1out) {
    const int bi = blockIdx.x;            // b*N + i
    const int b = bi >> 11;
    const int i = bi & (NN - 1);
    const int o = threadIdx.x;            // 0..63
    __shared__ float xm[192];
    __shared__ float xjs[30][3];
    const float* xb = x + (size_t)b * 3 * NN;
    float xi0 = xb[i], xi1 = xb[NN + i], xi2 = xb[2 * NN + i];
    if (o < 30) {
        int j = idx30[(size_t)bi * 30 + o];
        xjs[o][0] = xb[j]; xjs[o][1] = xb[NN + j]; xjs[o][2] = xb[2 * NN + j];
    }
    float wl[6], wb[9], wc[7];
    #pragma unroll
    for (int c = 0; c < 6; ++c) wl[c] = w1l[o * 6 + c];
    #pragma unroll
    for (int c = 0; c < 9; ++c) wb[c] = w1b[o * 9 + c];
    #pragma unroll
    for (int c = 0; c < 7; ++c) wc[c] = w1c[o * 7 + c];
    float sl = bnscale(g1l[o]), bl = b1l[o];
    float sb = bnscale(g1b[o]), bbv = b1b[o];
    float sc = bnscale(g1c[o]), bc = b1c[o];
    __syncthreads();
    float aL = -INFINITY, aB = -INFINITY, aC = -INFINITY;
    for (int k = 0; k < 30; ++k) {
        float r0 = xjs[k][0] - xi0, r1 = xjs[k][1] - xi1, r2 = xjs[k][2] - xi2;
        float ss = r0 * r0 + r1 * r1 + r2 * r2;
        if (k < 5) {
            float y = wl[0]*r0 + wl[1]*r1 + wl[2]*r2 + wl[3]*xi0 + wl[4]*xi1 + wl[5]*xi2;
            aL = fmaxf(aL, leaky(y * sl + bl));
        }
        if (k < 20) {
            float nrm = sqrtf(ss) + 1e-8f;
            float y = wb[0]*r0 + wb[1]*r1 + wb[2]*r2
                    + wb[3]*(r0/nrm) + wb[4]*(r1/nrm) + wb[5]*(r2/nrm)
                    + wb[6]*xi0 + wb[7]*xi1 + wb[8]*xi2;
            aB = fmaxf(aB, leaky(y * sb + bbv));
        }
        {
            float d = sqrtf(ss);
            float y = wc[0]*r0 + wc[1]*r1 + wc[2]*r2 + wc[3]*xi0 + wc[4]*xi1 + wc[5]*xi2 + wc[6]*d;
            aC = fmaxf(aC, leaky(y * sc + bc));
        }
    }
    xm[o] = aL; xm[64 + o] = aB; xm[128 + o] = aC;
    __syncthreads();
    // wf conv: 192 -> 64
    const float* wr = wf + (size_t)o * 192;
    float y = 0.f;
    #pragma unroll 8
    for (int c = 0; c < 192; c += 4) {
        float4 wv = *(const float4*)(wr + c);
        float4 xv = *(const float4*)(&xm[c]);
        y += wv.x * xv.x + wv.y * xv.y + wv.z * xv.z + wv.w * xv.w;
    }
    y = leaky(y * bnscale(gf[o]) + bf_[o]);
    x1out[(size_t)bi * 64 + o] = y;
}

// ---------------------------------------------------------------------------
// Kernel 3: per-point squared norms over C (point-major input)
// ---------------------------------------------------------------------------
template<int C>
__global__ __launch_bounds__(256) void rownorm(const float* __restrict__ xin,
                                               float* __restrict__ nrm) {
    int i = blockIdx.x * 256 + threadIdx.x;     // 0..B*N-1
    const float* r = xin + (size_t)i * C;
    float s = 0.f;
    #pragma unroll 4
    for (int c = 0; c < C; c += 4) {
        float4 v = *(const float4*)(r + c);
        s += v.x * v.x + v.y * v.y + v.z * v.z + v.w * v.w;
    }
    nrm[i] = s;
}

// ---------------------------------------------------------------------------
// Kernel 4: top-20 on C-dim features (point-major). 4 rows per block.
// ---------------------------------------------------------------------------
template<int C>
__global__ __launch_bounds__(256) void topk_feat(const float* __restrict__ xin,
                                                 const float* __restrict__ nrm,
                                                 int* __restrict__ idx20) {
    const int tile = blockIdx.x;
    const int b = tile >> 9;
    const int i0 = (tile & 511) * 4;
    __shared__ float dist[4][NN];
    __shared__ float xi[4][C];
    const float* xb = xin + (size_t)b * NN * C;
    const int tid = threadIdx.x;
    for (int t = tid; t < 4 * C; t += 256)
        xi[t / C][t % C] = xb[(size_t)(i0 + t / C) * C + (t % C)];
    __syncthreads();
    float n0 = nrm[b * NN + i0 + 0], n1 = nrm[b * NN + i0 + 1];
    float n2 = nrm[b * NN + i0 + 2], n3 = nrm[b * NN + i0 + 3];
    for (int j = tid; j < NN; j += 256) {
        const float* xj = xb + (size_t)j * C;
        float d0 = 0.f, d1 = 0.f, d2 = 0.f, d3 = 0.f;
        #pragma unroll 4
        for (int c = 0; c < C; c += 4) {
            float4 v  = *(const float4*)(xj + c);
            float4 a0 = *(const float4*)(&xi[0][c]);
            float4 a1 = *(const float4*)(&xi[1][c]);
            float4 a2 = *(const float4*)(&xi[2][c]);
            float4 a3 = *(const float4*)(&xi[3][c]);
            d0 += v.x * a0.x + v.y * a0.y + v.z * a0.z + v.w * a0.w;
            d1 += v.x * a1.x + v.y * a1.y + v.z * a1.z + v.w * a1.w;
            d2 += v.x * a2.x + v.y * a2.y + v.z * a2.z + v.w * a2.w;
            d3 += v.x * a3.x + v.y * a3.y + v.z * a3.z + v.w * a3.w;
        }
        float nj = nrm[b * NN + j];
        dist[0][j] = 2.f * d0 - n0 - nj;
        dist[1][j] = 2.f * d1 - n1 - nj;
        dist[2][j] = 2.f * d2 - n2 - nj;
        dist[3][j] = 2.f * d3 - n3 - nj;
    }
    __syncthreads();
    const int w = tid >> 6;
    const int lane = tid & 63;
    float lv[32];
    #pragma unroll
    for (int m = 0; m < 32; ++m) lv[m] = dist[w][lane * 32 + m];
    wave_topk<20>(lv, lane, idx20 + ((size_t)b * NN + i0 + w) * 20);
}

// ---------------------------------------------------------------------------
// Kernel 5: edge conv: y[o] = max_k leaky(bn( sum_c w[o,c]*(xj-xi)[c] + w[o,C+c]*xi[c] ))
// Rewritten: t[o] = sum_c (w[o,C+c]-w[o,c])*xi[c];  y_k = t + sum_c w[o,c]*xj_k[c]
// LDS holds neighbors transposed [c][k] so inner loop does broadcast float4 reads.
// ---------------------------------------------------------------------------
__device__ __forceinline__ void acc20_update(float w1, const float* base, float acc[20]) {
    #pragma unroll
    for (int r = 0; r < 5; ++r) {
        float4 a = ((const float4*)base)[r];
        acc[4 * r + 0] += w1 * a.x;
        acc[4 * r + 1] += w1 * a.y;
        acc[4 * r + 2] += w1 * a.z;
        acc[4 * r + 3] += w1 * a.w;
    }
}

template<int C, int COUT, int PSUB>
__global__ __launch_bounds__(256) void edge_conv(
        const float* __restrict__ xin, const int* __restrict__ idx20,
        const float* __restrict__ w, const float* __restrict__ g,
        const float* __restrict__ bb, float* __restrict__ xout) {
    const int tile = blockIdx.x;                 // b*(N/PSUB) + it
    const int b = tile / (NN / PSUB);
    const int i0 = (tile % (NN / PSUB)) * PSUB;
    __shared__ float xjT[PSUB][C][20];
    __shared__ float xiL[PSUB][C];
    __shared__ int jl[PSUB][20];
    const int tid = threadIdx.x;
    if (tid < PSUB * 20)
        jl[tid / 20][tid % 20] = idx20[((size_t)b * NN + i0 + tid / 20) * 20 + tid % 20];
    for (int t = tid; t < PSUB * C; t += 256)
        xiL[t / C][t % C] = xin[((size_t)b * NN + i0 + t / C) * C + (t % C)];
    __syncthreads();
    for (int t = tid; t < PSUB * 20 * C; t += 256) {
        int p = t / (20 * C);
        int r = t % (20 * C);
        int k = r / C;
        int c = r % C;
        int j = jl[p][k];
        xjT[p][c][k] = xin[((size_t)b * NN + j) * C + c];
    }
    __syncthreads();
    const int p = tid / COUT;
    const int o = tid % COUT;
    const float* wrow = w + (size_t)o * 2 * C;
    float acc[20];
    #pragma unroll
    for (int k = 0; k < 20; ++k) acc[k] = 0.f;
    float tterm = 0.f;
    #pragma unroll 2
    for (int c = 0; c < C; c += 4) {
        float4 wa  = *(const float4*)(wrow + c);
        float4 wb2 = *(const float4*)(wrow + C + c);
        float4 xi4 = *(const float4*)(&xiL[p][c]);
        tterm += (wb2.x - wa.x) * xi4.x + (wb2.y - wa.y) * xi4.y
               + (wb2.z - wa.z) * xi4.z + (wb2.w - wa.w) * xi4.w;
        acc20_update(wa.x, &xjT[p][c + 0][0], acc);
        acc20_update(wa.y, &xjT[p][c + 1][0], acc);
        acc20_update(wa.z, &xjT[p][c + 2][0], acc);
        acc20_update(wa.w, &xjT[p][c + 3][0], acc);
    }
    float s = bnscale(g[o]), bv = bb[o];
    float best = -INFINITY;
    #pragma unroll
    for (int k = 0; k < 20; ++k) {
        float z = leaky((acc[k] + tterm) * s + bv);
        best = fmaxf(best, z);
    }
    xout[((size_t)b * NN + i0 + p) * COUT + o] = best;
}

// ---------------------------------------------------------------------------
// Kernel 6: w5 conv (512->1024) + bn + leaky, fused partial max/sum over 16-pt chunks
// ---------------------------------------------------------------------------
__global__ __launch_bounds__(256) void conv5_pool(
        const float* __restrict__ x1, const float* __restrict__ x2,
        const float* __restrict__ x3, const float* __restrict__ x4,
        const float* __restrict__ w5, const float* __restrict__ g5,
        const float* __restrict__ b5,
        float* __restrict__ pmax, float* __restrict__ psum) {
    const int blk = blockIdx.x;                  // b*128 + chunk
    const int b = blk >> 7;
    const int ch = blk & 127;
    const int i0 = ch * 16;
    __shared__ float xt[16][512];
    const int tid = threadIdx.x;
    for (int t = tid; t < 16 * 512; t += 256) {
        int p = t >> 9, c = t & 511;
        size_t pi = (size_t)b * NN + i0 + p;
        float v;
        if (c < 64)       v = x1[pi * 64 + c];
        else if (c < 128) v = x2[pi * 64 + (c - 64)];
        else if (c < 256) v = x3[pi * 128 + (c - 128)];
        else              v = x4[pi * 256 + (c - 256)];
        xt[p][c] = v;
    }
    __syncthreads();
    float acc[4][16];
    #pragma unroll
    for (int q = 0; q < 4; ++q)
        #pragma unroll
        for (int p = 0; p < 16; ++p) acc[q][p] = 0.f;
    for (int c = 0; c < 512; c += 4) {
        float4 wv[4];
        #pragma unroll
        for (int q = 0; q < 4; ++q)
            wv[q] = *(const float4*)(w5 + (size_t)(tid + 256 * q) * 512 + c);
        #pragma unroll
        for (int p = 0; p < 16; ++p) {
            float4 xv = *(const float4*)(&xt[p][c]);
            #pragma unroll
            for (int q = 0; q < 4; ++q)
                acc[q][p] += wv[q].x * xv.x + wv[q].y * xv.y + wv[q].z * xv.z + wv[q].w * xv.w;
        }
    }
    #pragma unroll
    for (int q = 0; q < 4; ++q) {
        int oc = tid + 256 * q;
        float s = bnscale(g5[oc]), bv = b5[oc];
        float m = -INFINITY, sm = 0.f;
        #pragma unroll
        for (int p = 0; p < 16; ++p) {
            float z = leaky(acc[q][p] * s + bv);
            m = fmaxf(m, z);
            sm += z;
        }
        pmax[((size_t)b * 128 + ch) * 1024 + oc] = m;
        psum[((size_t)b * 128 + ch) * 1024 + oc] = sm;
    }
}

// ---------------------------------------------------------------------------
// Kernel 7: final reduce (max/mean) + 3 FC layers. One block per batch row.
// ---------------------------------------------------------------------------
__global__ __launch_bounds__(256) void fc_head(
        const float* __restrict__ pmax, const float* __restrict__ psum,
        const float* __restrict__ wl1, const float* __restrict__ g6, const float* __restrict__ b6,
        const float* __restrict__ wl2, const float* __restrict__ bl2,
        const float* __restrict__ g7, const float* __restrict__ b7,
        const float* __restrict__ wl3, const float* __restrict__ bl3,
        float* __restrict__ out) {
    const int b = blockIdx.x;
    const int tid = threadIdx.x;
    __shared__ float h[2048];
    __shared__ float h1[512];
    __shared__ float h2[256];
    #pragma unroll
    for (int q = 0; q < 4; ++q) {
        int oc = tid + 256 * q;
        float m = -INFINITY, sm = 0.f;
        for (int ch = 0; ch < 128; ++ch) {
            m = fmaxf(m, pmax[((size_t)b * 128 + ch) * 1024 + oc]);
            sm += psum[((size_t)b * 128 + ch) * 1024 + oc];
        }
        h[oc] = m;
        h[1024 + oc] = sm * (1.0f / 2048.0f);
    }
    __syncthreads();
    #pragma unroll
    for (int q = 0; q < 2; ++q) {
        int o = tid + 256 * q;
        const float* wr = wl1 + (size_t)o * 2048;
        float y = 0.f;
        for (int c = 0; c < 2048; c += 4) {
            float4 wv = *(const float4*)(wr + c);
            float4 hv = *(const float4*)(&h[c]);
            y += wv.x * hv.x + wv.y * hv.y + wv.z * hv.z + wv.w * hv.w;
        }
        y = y * bnscale(g6[o]) + b6[o];
        h1[o] = leaky(y);
    }
    __syncthreads();
    {
        int o = tid;
        const float* wr = wl2 + (size_t)o * 512;
        float y = 0.f;
        for (int c = 0; c < 512; c += 4) {
            float4 wv = *(const float4*)(wr + c);
            float4 hv = *(const float4*)(&h1[c]);
            y += wv.x * hv.x + wv.y * hv.y + wv.z * hv.z + wv.w * hv.w;
        }
        y = (y + bl2[o]) * bnscale(g7[o]) + b7[o];
        h2[o] = leaky(y);
    }
    __syncthreads();
    if (tid < 7) {
        const float* wr = wl3 + tid * 256;
        float y = 0.f;
        for (int c = 0; c < 256; ++c) y += wr[c] * h2[c];
        out[b * 7 + tid] = y + bl3[tid];
    }
}

// ---------------------------------------------------------------------------
extern "C" void kernel_launch(void* const* d_in, const int* in_sizes, int n_in,
                              void* d_out, int out_size, void* d_ws, size_t ws_size,
                              hipStream_t stream) {
    const float* x   = (const float*)d_in[0];
    const float* w1l = (const float*)d_in[1];
    const float* g1l = (const float*)d_in[2];
    const float* b1l = (const float*)d_in[3];
    const float* w1b = (const float*)d_in[4];
    const float* g1b = (const float*)d_in[5];
    const float* b1b = (const float*)d_in[6];
    const float* w1c = (const float*)d_in[7];
    const float* g1c = (const float*)d_in[8];
    const float* b1c = (const float*)d_in[9];
    const float* wf  = (const float*)d_in[10];
    const float* gf  = (const float*)d_in[11];
    const float* bf_ = (const float*)d_in[12];
    const float* w2  = (const float*)d_in[13];
    const float* g2  = (const float*)d_in[14];
    const float* b2  = (const float*)d_in[15];
    const float* w3  = (const float*)d_in[16];
    const float* g3  = (const float*)d_in[17];
    const float* b3  = (const float*)d_in[18];
    const float* w4  = (const float*)d_in[19];
    const float* g4  = (const float*)d_in[20];
    const float* b4  = (const float*)d_in[21];
    const float* w5  = (const float*)d_in[22];
    const float* g5  = (const float*)d_in[23];
    const float* b5  = (const float*)d_in[24];
    const float* wl1 = (const float*)d_in[25];
    const float* g6  = (const float*)d_in[26];
    const float* b6  = (const float*)d_in[27];
    const float* wl2 = (const float*)d_in[28];
    const float* bl2 = (const float*)d_in[29];
    const float* g7  = (const float*)d_in[30];
    const float* b7  = (const float*)d_in[31];
    const float* wl3 = (const float*)d_in[32];
    const float* bl3 = (const float*)d_in[33];
    float* out = (float*)d_out;

    char* ws = (char*)d_ws;
    int*   idxb = (int*)(ws);                          // 32768*30 ints (3.75 MB)
    float* x1   = (float*)(ws + ((size_t)4  << 20));   // [B,N,64]   8 MB
    float* x2   = (float*)(ws + ((size_t)12 << 20));   // [B,N,64]   8 MB
    float* x3   = (float*)(ws + ((size_t)20 << 20));   // [B,N,128] 16 MB
    float* x4   = (float*)(ws + ((size_t)36 << 20));   // [B,N,256] 32 MB
    float* nrm  = (float*)(ws + ((size_t)68 << 20));   // [B*N]
    float* pmax = (float*)(ws + ((size_t)69 << 20));   // [B,128,1024] 8 MB
    float* psum = (float*)(ws + ((size_t)77 << 20));   // [B,128,1024] 8 MB

    // 1. top-30 on xyz
    topk_xyz<<<BB * NN / 4, 256, 0, stream>>>(x, idxb);
    // 2. hierarchical scale convs + wf conv -> x1
    hier_conv<<<BB * NN, 64, 0, stream>>>(x, idxb, w1l, g1l, b1l, w1b, g1b, b1b,
                                          w1c, g1c, b1c, wf, gf, bf_, x1);
    // 3. edge conv stage 2: x1(64) -> x2(64)
    rownorm<64><<<BB * NN / 256, 256, 0, stream>>>(x1, nrm);
    topk_feat<64><<<BB * NN / 4, 256, 0, stream>>>(x1, nrm, idxb);
    edge_conv<64, 64, 4><<<BB * NN / 4, 256, 0, stream>>>(x1, idxb, w2, g2, b2, x2);
    // 4. edge conv stage 3: x2(64) -> x3(128)
    rownorm<64><<<BB * NN / 256, 256, 0, stream>>>(x2, nrm);
    topk_feat<64><<<BB * NN / 4, 256, 0, stream>>>(x2, nrm, idxb);
    edge_conv<64, 128, 2><<<BB * NN / 2, 256, 0, stream>>>(x2, idxb, w3, g3, b3, x3);
    // 5. edge conv stage 4: x3(128) -> x4(256)
    rownorm<128><<<BB * NN / 256, 256, 0, stream>>>(x3, nrm);
    topk_feat<128><<<BB * NN / 4, 256, 0, stream>>>(x3, nrm, idxb);
    edge_conv<128, 256, 1><<<BB * NN, 256, 0, stream>>>(x3, idxb, w4, g4, b4, x4);
    // 6. w5 conv + pooling partials
    conv5_pool<<<BB * 128, 256, 0, stream>>>(x1, x2, x3, x4, w5, g5, b5, pmax, psum);
    // 7. reduce + FC head
    fc_head<<<BB, 256, 0, stream>>>(pmax, psum, wl1, g6, b6, wl2, bl2, g7, b7,
                                    wl3, bl3, out);
}